// Round 5
// baseline (333.110 us; speedup 1.0000x reference)
//
#include <hip/hip_runtime.h>
#include <hip/hip_bf16.h>
#include <math.h>

#define D 128
#define L 200
#define BATCH 4096
#define N_ITEMS 100000
#define NI1 (N_ITEMS + 1)
#define KWBLOCKS 782            // ceil(NI1/128)
#define QWBLOCKS 32             // 4096/128
#define HALF_CNT (BATCH * L / 2)   // 409600, threefry counter split
#define TAU_INV 0.25f
#define SIG_Q 0.1f
// C_KL = log(SIG_P/SIG_Q) + SIG_Q^2/2 - 0.5  (SIG_P = 1)
#define C_KL 1.8075850929940455f
// fp8 e4m3 software decode: val = as_float((s<<31)|(e<<23)|(m<<20)) * 2^113 (x128 scale folded)
#define C_DEC 1.03845937e34f

typedef __attribute__((ext_vector_type(8))) short short8;
typedef __attribute__((ext_vector_type(4))) float float4v;
typedef __attribute__((ext_vector_type(2))) float f32x2;

#if defined(__has_builtin)
#if __has_builtin(__builtin_amdgcn_cvt_pk_f32_fp8) && __has_builtin(__builtin_amdgcn_cvt_pk_fp8_f32)
#define HWFP8 1
#endif
#endif
#ifndef HWFP8
#define HWFP8 0
#endif

// ---------------- bf16 / fp8 helpers ----------------
__device__ __forceinline__ unsigned short f2bf(float f) {
    unsigned x = __float_as_uint(f);
    unsigned r = (x + 0x7fffu + ((x >> 16) & 1u)) >> 16;  // RNE
    return (unsigned short)r;
}
// f32 -> fp8 e4m3fn (OCP), RNE; |x| < 448 guaranteed by data (~N(0,1.3) after x128)
__device__ __forceinline__ unsigned f2fp8(float x) {
    unsigned s = (__float_as_uint(x) >> 31) << 7;
    float ay = fabsf(x);
    unsigned b;
    if (ay < 0.015625f) {                       // subnormal: step 2^-9; n==8 carries to e=1
        b = (unsigned)__float2int_rn(ay * 512.0f);
    } else {
        unsigned u = __float_as_uint(ay);
        u += 0x7ffffu + ((u >> 20) & 1u);       // RNE at mantissa bit 20
        unsigned e = (u >> 23) - 120u;          // bias 127 -> 7
        b = (e << 3) | ((u >> 20) & 7u);
    }
    return b | s;
}

// pack 4 (already x128-scaled) floats into 4 fp8 bytes of one dword
__device__ __forceinline__ unsigned pack4fp8(float a, float b, float c, float d) {
#if HWFP8
    int r = __builtin_amdgcn_cvt_pk_fp8_f32(a, b, 0, false);
    r = __builtin_amdgcn_cvt_pk_fp8_f32(c, d, r, true);
    return (unsigned)r;
#else
    return f2fp8(a) | (f2fp8(b) << 8) | (f2fp8(c) << 16) | (f2fp8(d) << 24);
#endif
}

// decode 4 fp8 bytes -> two f32 pairs, each = true_value * 128
#if HWFP8
__device__ __forceinline__ void dec4p(unsigned x, f32x2& lo, f32x2& hi) {
    lo = __builtin_amdgcn_cvt_pk_f32_fp8(x, false);
    hi = __builtin_amdgcn_cvt_pk_f32_fp8(x, true);
}
#else
__device__ __forceinline__ void dec4p(unsigned x, f32x2& lo, f32x2& hi) {
    const float S = C_DEC * 128.f;
    lo.x = __uint_as_float(((x & 0x80u) << 24) | ((x & 0x7fu) << 20)) * S;
    lo.y = __uint_as_float(((x & 0x8000u) << 16) | ((x & 0x7f00u) << 12)) * S;
    hi.x = __uint_as_float(((x & 0x800000u) << 8) | ((x & 0x7f0000u) << 4)) * S;
    hi.y = __uint_as_float((x & 0x80000000u) | ((x & 0x7f000000u) >> 4)) * S;
}
#endif

__device__ __forceinline__ f32x2 pfma(f32x2 a, f32x2 b, f32x2 c) {
    return __builtin_elementwise_fma(a, b, c);
}

// 32-lane all-reduce sum: 4 DPP adds + 1 ds_swizzle
#define DPP_ADD(x, ctrl)                                                     \
    ((x) + __uint_as_float((unsigned)__builtin_amdgcn_update_dpp(            \
               0, (int)__float_as_uint(x), ctrl, 0xF, 0xF, true)))
__device__ __forceinline__ float red32(float x) {
    x = DPP_ADD(x, 0xB1);    // quad_perm [1,0,3,2]  : xor 1
    x = DPP_ADD(x, 0x4E);    // quad_perm [2,3,0,1]  : xor 2
    x = DPP_ADD(x, 0x141);   // row_half_mirror      : pairs 8-groups
    x = DPP_ADD(x, 0x140);   // row_mirror           : pairs 16-groups
    x += __uint_as_float((unsigned)__builtin_amdgcn_ds_swizzle(
        (int)__float_as_uint(x), 0x401F));   // xor 16 within 32
    return x;
}

// ---------------- JAX threefry2x32 (exact) ----------------
__device__ __forceinline__ unsigned rotl32(unsigned x, int r) {
    return (x << r) | (x >> (32 - r));
}

__device__ __forceinline__ void threefry2x32(unsigned k0, unsigned k1,
                                             unsigned x0, unsigned x1,
                                             unsigned& o0, unsigned& o1) {
    unsigned k2 = k0 ^ k1 ^ 0x1BD11BDAu;
    x0 += k0; x1 += k1;
#define TF_ROUND(r) { x0 += x1; x1 = rotl32(x1, r); x1 ^= x0; }
    TF_ROUND(13) TF_ROUND(15) TF_ROUND(26) TF_ROUND(6)
    x0 += k1; x1 += k2 + 1u;
    TF_ROUND(17) TF_ROUND(29) TF_ROUND(16) TF_ROUND(24)
    x0 += k2; x1 += k0 + 2u;
    TF_ROUND(13) TF_ROUND(15) TF_ROUND(26) TF_ROUND(6)
    x0 += k0; x1 += k1 + 3u;
    TF_ROUND(17) TF_ROUND(29) TF_ROUND(16) TF_ROUND(24)
    x0 += k1; x1 += k2 + 4u;
    TF_ROUND(13) TF_ROUND(15) TF_ROUND(26) TF_ROUND(6)
    x0 += k2; x1 += k0 + 5u;
#undef TF_ROUND
    o0 = x0; o1 = x1;
}

// XLA ErfInv32 (Giles) polynomial
__device__ float erfinv_f32(float x) {
    float w = -log1pf(-x * x);
    float p;
    if (w < 5.0f) {
        w -= 2.5f;
        p = 2.81022636e-08f;
        p = fmaf(p, w, 3.43273939e-07f);
        p = fmaf(p, w, -3.5233877e-06f);
        p = fmaf(p, w, -4.39150654e-06f);
        p = fmaf(p, w, 0.00021858087f);
        p = fmaf(p, w, -0.00125372503f);
        p = fmaf(p, w, -0.00417768164f);
        p = fmaf(p, w, 0.246640727f);
        p = fmaf(p, w, 1.50140941f);
    } else {
        w = sqrtf(w) - 3.0f;
        p = -0.000200214257f;
        p = fmaf(p, w, 0.000100950558f);
        p = fmaf(p, w, 0.00134934322f);
        p = fmaf(p, w, -0.00367342844f);
        p = fmaf(p, w, 0.00573950773f);
        p = fmaf(p, w, -0.0076224613f);
        p = fmaf(p, w, 0.00943887047f);
        p = fmaf(p, w, 1.00167406f);
        p = fmaf(p, w, 2.83297682f);
    }
    return p * x;
}

__device__ float bits_to_normal(unsigned bits) {
    float f = __uint_as_float((bits >> 9) | 0x3f800000u) - 1.0f;
    const float mn = -0.99999994f;
    float scale = 1.0f - mn;              // rounds to 2.0f, matches XLA
    float u = fmaf(f, scale, mn);
    u = fmaxf(mn, u);
    return 1.4142135623730951f * erfinv_f32(u);
}

// ---- prep: WkTb[n][k], WqTb[n][k] = bf16 transposes; zero accum ----
__global__ __launch_bounds__(128) void wk_prep(const float* __restrict__ Wk,
                                               const float* __restrict__ Wq,
                                               unsigned short* __restrict__ WkTb,
                                               unsigned short* __restrict__ WqTb,
                                               float* __restrict__ accum) {
    int n = blockIdx.x & 127;
    const float* src = (blockIdx.x < 128) ? Wk : Wq;
    unsigned short* dst = (blockIdx.x < 128) ? WkTb : WqTb;
    int k = threadIdx.x;
    dst[n * D + k] = f2bf(src[k * D + n]);
    if (blockIdx.x == 0 && k == 0) {
        accum[0] = 0.f;
        ((unsigned*)accum)[1] = 0u;
    }
}

// ---- tables: PT packed rows (256 B/item): chunk c in [0,32):
//      bytes [8c..8c+3] = fp8(KW[row][4c..4c+3] * 128),
//      bytes [8c+4..8c+7] = fp8(item_emb[row][4c..4c+3] * 128).
//      KW computed TRANSPOSED (mfma(WkT, emb)) so each lane owns 4 consecutive
//      columns -> one packed dword. Full row image staged in LDS (XOR-swizzled
//      16B units) and streamed out as coalesced dwordx4.
//      Also qW = user_emb[user_idx]@Wq + b_att (f32). ----
__global__ __launch_bounds__(256) void tables_kernel(
    const float* __restrict__ item_emb, const float* __restrict__ user_emb,
    const int* __restrict__ user_idx,
    const unsigned short* __restrict__ WkTb, const unsigned short* __restrict__ WqTb,
    const float* __restrict__ b_att,
    unsigned char* __restrict__ PT, float* __restrict__ qW) {
    __shared__ unsigned char stage[128 * 256];   // 32 KB
    int t = threadIdx.x;
    int w = t >> 6, lane = t & 63;
    int lq = lane >> 4, lm = lane & 15;
    int bx = blockIdx.x;

    if (bx < KWBLOCKS) {
        int r0 = bx * 128;
        int rw = w * 32;                         // wave-local row base
        short8 afr[2][4];
#pragma unroll
        for (int tm = 0; tm < 2; tm++) {
            int rowl = rw + tm * 16 + lm;
            int row = r0 + rowl;
            bool ok = row < NI1;
            const float* src = item_emb + (size_t)row * D;
            unsigned sbase = rowl * 256;
            int rsw = rowl & 15;
#pragma unroll
            for (int kc = 0; kc < 4; kc++) {
                float4 a = ok ? *(const float4*)(src + kc * 32 + lq * 8)
                              : make_float4(0.f, 0.f, 0.f, 0.f);
                float4 c = ok ? *(const float4*)(src + kc * 32 + lq * 8 + 4)
                              : make_float4(0.f, 0.f, 0.f, 0.f);
                short8 f;
                f[0] = (short)f2bf(a.x); f[1] = (short)f2bf(a.y);
                f[2] = (short)f2bf(a.z); f[3] = (short)f2bf(a.w);
                f[4] = (short)f2bf(c.x); f[5] = (short)f2bf(c.y);
                f[6] = (short)f2bf(c.z); f[7] = (short)f2bf(c.w);
                afr[tm][kc] = f;
                // emb fp8 -> V slots of chunks c0, c0+1 (bytes 4-7 / 12-15 of unit u)
                int u = kc * 4 + lq;             // = (kc*8+lq*2)>>1
                unsigned* dst = (unsigned*)(stage + sbase + ((unsigned)(u ^ rsw) << 4));
                dst[1] = pack4fp8(a.x * 128.f, a.y * 128.f, a.z * 128.f, a.w * 128.f);
                dst[3] = pack4fp8(c.x * 128.f, c.y * 128.f, c.z * 128.f, c.w * 128.f);
            }
        }
        float4v acc[2][8];
#pragma unroll
        for (int tm = 0; tm < 2; tm++)
#pragma unroll
            for (int tn = 0; tn < 8; tn++) acc[tm][tn] = (float4v)(0.f);
#pragma unroll
        for (int tn = 0; tn < 8; tn++) {
#pragma unroll
            for (int kc = 0; kc < 4; kc++) {
                short8 bfr = *(const short8*)(WkTb + (tn * 16 + lm) * D + kc * 32 + lq * 8);
                // TRANSPOSED: D[m'=WkT row][n'=item row] => lane holds 4 consecutive KW cols
                acc[0][tn] = __builtin_amdgcn_mfma_f32_16x16x32_bf16(bfr, afr[0][kc], acc[0][tn], 0, 0, 0);
                acc[1][tn] = __builtin_amdgcn_mfma_f32_16x16x32_bf16(bfr, afr[1][kc], acc[1][tn], 0, 0, 0);
            }
        }
#pragma unroll
        for (int tm = 0; tm < 2; tm++) {
            int rowl = rw + tm * 16 + lm;        // n' = lane&15
            int rsw = rowl & 15;
            unsigned sbase = rowl * 256;
#pragma unroll
            for (int tn = 0; tn < 8; tn++) {
                unsigned dw = pack4fp8(acc[tm][tn][0] * 128.f, acc[tm][tn][1] * 128.f,
                                       acc[tm][tn][2] * 128.f, acc[tm][tn][3] * 128.f);
                int cc = 4 * tn + lq;            // chunk (4 consecutive dims)
                int u = cc >> 1;
                *(unsigned*)(stage + sbase + ((unsigned)(u ^ rsw) << 4) +
                             ((unsigned)(cc & 1) << 3)) = dw;
            }
        }
        __syncthreads();
        // coalesced write-out: 128 rows x 16 units of 16B
#pragma unroll
        for (int i = 0; i < 8; i++) {
            int gidx = i * 256 + t;
            int rowl = gidx >> 4, u = gidx & 15;
            int row = r0 + rowl;
            if (row < NI1) {
                float4 vv = *(const float4*)(stage + rowl * 256 +
                                             ((unsigned)(u ^ (rowl & 15)) << 4));
                *(float4*)(PT + (size_t)row * 256 + (unsigned)u * 16) = vv;
            }
        }
    } else {
        int r0 = (bx - KWBLOCKS) * 128 + w * 32;
        int urow0 = user_idx[r0 + lm];
        int urow1 = user_idx[r0 + 16 + lm];
        short8 afr[2][4];
#pragma unroll
        for (int tm = 0; tm < 2; tm++) {
            const float* src = user_emb + (size_t)(tm ? urow1 : urow0) * D;
#pragma unroll
            for (int kc = 0; kc < 4; kc++) {
                float4 a = *(const float4*)(src + kc * 32 + lq * 8);
                float4 c = *(const float4*)(src + kc * 32 + lq * 8 + 4);
                short8 f;
                f[0] = (short)f2bf(a.x); f[1] = (short)f2bf(a.y);
                f[2] = (short)f2bf(a.z); f[3] = (short)f2bf(a.w);
                f[4] = (short)f2bf(c.x); f[5] = (short)f2bf(c.y);
                f[6] = (short)f2bf(c.z); f[7] = (short)f2bf(c.w);
                afr[tm][kc] = f;
            }
        }
        float4v acc[2][8];
#pragma unroll
        for (int tm = 0; tm < 2; tm++)
#pragma unroll
            for (int tn = 0; tn < 8; tn++) acc[tm][tn] = (float4v)(0.f);
#pragma unroll
        for (int tn = 0; tn < 8; tn++) {
#pragma unroll
            for (int kc = 0; kc < 4; kc++) {
                short8 bfr = *(const short8*)(WqTb + (tn * 16 + lm) * D + kc * 32 + lq * 8);
                acc[0][tn] = __builtin_amdgcn_mfma_f32_16x16x32_bf16(afr[0][kc], bfr, acc[0][tn], 0, 0, 0);
                acc[1][tn] = __builtin_amdgcn_mfma_f32_16x16x32_bf16(afr[1][kc], bfr, acc[1][tn], 0, 0, 0);
            }
        }
#pragma unroll
        for (int tm = 0; tm < 2; tm++)
#pragma unroll
            for (int tn = 0; tn < 8; tn++) {
                float bv = b_att[tn * 16 + lm];
#pragma unroll
                for (int i = 0; i < 4; i++) {
                    int row = r0 + tm * 16 + lq * 4 + i;
                    qW[(size_t)row * D + tn * 16 + lm] = acc[tm][tn][i] + bv;
                }
            }
    }
}

// scaled-tanh coefficients: t = x*(1 - x^2/3 + 2x^4/15 - 17x^6/315) with x' = 128x
// folded: t' = x'*(1 + TC1*x'^2 + TC2*x'^4 + TC3*x'^6), t = t'/128 (folded into v)
#define TC3 (-1.2270929e-14f)   // -17/315 * 2^-42
#define TC2 (4.9670537e-10f)    //  2/15  * 2^-28
#define TC1 (-2.0345052e-5f)    // -1/3   * 2^-14

// ------- fused: single-pass stream (score+exp+sample+ctx) + KL + LN + logit ----
// VGPR-diet revision: 2-slot prefetch (depth-3 proved worthless, R4), no itb/vmask
// arrays -- validity recomputed from a refer[] LDS broadcast at use time. Target:
// natural allocation <= 64 VGPR -> 8 waves/SIMD (R0 evidence: occupancy tracks the
// VGPR bin). NO min-waves clause (R2: forcing it -> 643MB scratch spills).
__global__ __launch_bounds__(256) void fused_kernel(
    const unsigned char* __restrict__ PT, const float* __restrict__ qW,
    const float* __restrict__ v_att,
    const float* __restrict__ user_emb, const float* __restrict__ item_emb,
    const int* __restrict__ user_hist, const int* __restrict__ user_idx,
    const int* __restrict__ item_idx,
    const float* __restrict__ ln_u_g, const float* __restrict__ ln_u_b,
    const float* __restrict__ ln_i_g, const float* __restrict__ ln_i_b,
    const float* __restrict__ pred_W, const float* __restrict__ pred_b,
    float* __restrict__ out, float* __restrict__ kl_sum,
    unsigned int* __restrict__ kl_cnt) {
    int b = blockIdx.x;
    int t = threadIdx.x;
    int g = t >> 5, ln5 = t & 31, w_ = t >> 6, lane = t & 63;
    __shared__ int refer[L];
    __shared__ float2 r12[L];          // exp(SIG_Q*eps) pre-factors, score-independent
    __shared__ float4 gsA[8];          // per group: se, sw1, sw2, cnt
    __shared__ float2 gsB[8];          // per group: ss, ss2
    __shared__ float paccU[8][D], paccI[8][D];
    __shared__ float us_s[D];
    __shared__ float wredA[4], wredB[4], wredC[4];

    int u = user_idx[b], tgt = item_idx[b];
    if (t < L) refer[t] = user_hist[(size_t)u * L + t];

    float4 q4 = *(const float4*)(qW + (size_t)b * D + ln5 * 4);
    float4 v4 = *(const float4*)(v_att + ln5 * 4);
    // q scaled by 128 (x' domain), v scaled by 1/(128*tau)
    f32x2 qA = {q4.x * 128.f, q4.y * 128.f};
    f32x2 qB = {q4.z * 128.f, q4.w * 128.f};
    const float VS = TAU_INV / 128.f;
    f32x2 vAs = {v4.x * VS, v4.y * VS};
    f32x2 vBs = {v4.z * VS, v4.w * VS};

    __syncthreads();                   // refer[] ready

    // ---- Prologue: issue gathers for chunks 0..1 (10 loads in flight) ----
    int l0 = g * 25;
    uint2 kvb[2][5];
    unsigned lnoff = (unsigned)(ln5 * 8);
#pragma unroll
    for (int c0 = 0; c0 < 2; c0++) {
#pragma unroll
        for (int j = 0; j < 5; j++) {
            unsigned it = (unsigned)refer[l0 + c0 * 5 + j];
            kvb[c0][j] = *(const uint2*)(PT + ((it << 8) | lnoff));
        }
    }

    // ---- Phase A: random pre-factors r = exp(SIG_Q*eps); overlaps gather latency ----
    if (t < L) {
        int f = b * L + t;
        unsigned o0, o1, bits1, bits2;
        if (f < HALF_CNT) {
            threefry2x32(0u, 1u, (unsigned)f, (unsigned)(f + HALF_CNT), o0, o1);
            bits1 = o0;
            threefry2x32(0u, 2u, (unsigned)f, (unsigned)(f + HALF_CNT), o0, o1);
            bits2 = o0;
        } else {
            threefry2x32(0u, 1u, (unsigned)(f - HALF_CNT), (unsigned)f, o0, o1);
            bits1 = o1;
            threefry2x32(0u, 2u, (unsigned)(f - HALF_CNT), (unsigned)f, o0, o1);
            bits2 = o1;
        }
        r12[t] = make_float2(__expf(SIG_Q * bits_to_normal(bits1)),
                             __expf(SIG_Q * bits_to_normal(bits2)));
    }
    __syncthreads();                   // r12[] ready

    // ---- Phase B: 5 chunks x 5 rows; double-buffered (chunk c+2 refills slot
    //      c&1 right after chunk c is consumed) ----
    f32x2 aU01 = {0.f, 0.f}, aU23 = {0.f, 0.f};
    f32x2 aI01 = {0.f, 0.f}, aI23 = {0.f, 0.f};
    float se = 0.f, sw1 = 0.f, sw2 = 0.f, ss = 0.f, ss2 = 0.f, cn = 0.f;
    const f32x2 tc3v = {TC3, TC3}, tc2v = {TC2, TC2}, tc1v = {TC1, TC1};
    const f32x2 onev = {1.f, 1.f};
#pragma unroll
    for (int c = 0; c < 5; c++) {
        const int cur = c & 1;         // compile-time (full unroll) -> registers
#pragma unroll
        for (int j = 0; j < 5; j++) {
            unsigned kx = kvb[cur][j].x, ky = kvb[cur][j].y;
            f32x2 kA, kB;
            dec4p(kx, kA, kB);                 // = k_true * 128
            f32x2 xA = kA + qA, xB = kB + qB;  // x' = 128*(k+q)
            f32x2 x2A = xA * xA, x2B = xB * xB;
            f32x2 pA = pfma(x2A, tc3v, tc2v);
            f32x2 pB = pfma(x2B, tc3v, tc2v);
            pA = pfma(x2A, pA, tc1v);
            pB = pfma(x2B, pB, tc1v);
            pA = pfma(x2A, pA, onev);
            pB = pfma(x2B, pB, onev);
            f32x2 pr = (xA * pA) * vAs;
            pr = pfma(xB * pB, vBs, pr);
            float s = red32(pr.x + pr.y);
            int it = refer[l0 + c * 5 + j];     // LDS broadcast (group-uniform)
            bool valid = (it != tgt) && (it != N_ITEMS);
            float e = valid ? __expf(s) : 0.f;  // |s|<=~0.6, no max-shift
            float sm = valid ? s : 0.f;
            se += e; ss += sm; ss2 = fmaf(sm, sm, ss2);
            cn += valid ? 1.f : 0.f;
            float2 r = r12[l0 + c * 5 + j];
            float ed = e * 0.0078125f;          // fold V decode scale (1/128)
            float w1 = ed * r.x, w2 = ed * r.y;
            sw1 += w1; sw2 += w2;               // scaled; fixed in Phase C
            f32x2 vvA, vvB;
            dec4p(ky, vvA, vvB);                // = v_true * 128
            f32x2 w1v = {w1, w1}, w2v = {w2, w2};
            aU01 = pfma(w1v, vvA, aU01); aU23 = pfma(w1v, vvB, aU23);
            aI01 = pfma(w2v, vvA, aI01); aI23 = pfma(w2v, vvB, aI23);
        }
        if (c < 3) {                   // refill consumed slot with chunk c+2
#pragma unroll
            for (int j = 0; j < 5; j++) {
                unsigned it = (unsigned)refer[l0 + (c + 2) * 5 + j];
                kvb[cur][j] = *(const uint2*)(PT + ((it << 8) | lnoff));
            }
        }
    }
    if (ln5 == 0) {
        gsA[g] = make_float4(se, sw1, sw2, cn);
        gsB[g] = make_float2(ss, ss2);
    }
    *(float4*)&paccU[g][ln5 * 4] = make_float4(aU01.x, aU01.y, aU23.x, aU23.y);
    *(float4*)&paccI[g][ln5 * 4] = make_float4(aI01.x, aI01.y, aI23.x, aI23.y);
    __syncthreads();

    // ---- Phase C: combine scalars (uniform, all threads) ----
    float sum_e = 0.f, sum_w1 = 0.f, sum_w2 = 0.f, cntf = 0.f, ssum = 0.f, ss2um = 0.f;
#pragma unroll
    for (int g2 = 0; g2 < 8; g2++) {
        float4 a = gsA[g2]; float2 c = gsB[g2];
        sum_e += a.x; sum_w1 += a.y; sum_w2 += a.z; cntf += a.w;
        ssum += c.x; ss2um += c.y;
    }
    int n_valid_raw = (int)(cntf + 0.5f);
    int n_valid = n_valid_raw < 1 ? 1 : n_valid_raw;
    // KL closed form: sum_valid[C + 0.5*(s - T)^2], T = log(sum_e) - log(n)
    float T = __logf(sum_e + 1e-30f) - __logf((float)n_valid);
    float klb = cntf * C_KL +
                0.5f * (ss2um - 2.f * T * ssum + cntf * T * T);
    // sums of w were scaled by 1/128; ctx values are true-scale -> inv carries 1/128
    float inv1 = 0.0078125f / (sum_w1 + 1e-14f);
    float inv2 = 0.0078125f / (sum_w2 + 1e-14f);

    // ---- Phase D: ctx combine + LN + GMF + logit. half0=user, half1=item ----
    int d = t & 127, half = t >> 7;
    float ctx = 0.f;
    if (half) {
#pragma unroll
        for (int g2 = 0; g2 < 8; g2++) ctx += paccI[g2][d];
        ctx *= inv2;
    } else {
#pragma unroll
        for (int g2 = 0; g2 < 8; g2++) ctx += paccU[g2][d];
        ctx *= inv1;
    }
    float own = ctx * (half ? item_emb[(size_t)tgt * D + d]
                            : user_emb[(size_t)u * D + d]);
    float rsum = own;
#pragma unroll
    for (int m = 1; m < 64; m <<= 1) rsum += __shfl_xor(rsum, m);
    if (lane == 0) wredA[w_] = rsum;
    __syncthreads();
    float mean = (wredA[half * 2] + wredA[half * 2 + 1]) * (1.f / 128.f);
    float dv = own - mean;
    float vsum = dv * dv;
#pragma unroll
    for (int m = 1; m < 64; m <<= 1) vsum += __shfl_xor(vsum, m);
    if (lane == 0) wredB[w_] = vsum;
    __syncthreads();
    float var = (wredB[half * 2] + wredB[half * 2 + 1]) * (1.f / 128.f);
    float gg = half ? ln_i_g[d] : ln_u_g[d];
    float bb = half ? ln_i_b[d] : ln_u_b[d];
    float sl = dv * rsqrtf(var + 1e-5f) * gg + bb;
    if (!half) us_s[d] = sl;
    __syncthreads();
    float contrib = half ? (us_s[d] * sl * pred_W[d]) : 0.f;
#pragma unroll
    for (int m = 1; m < 64; m <<= 1) contrib += __shfl_xor(contrib, m);
    if (lane == 0) wredC[w_] = contrib;
    __syncthreads();
    if (t == 0) {
        out[b] = wredC[2] + wredC[3] + pred_b[0];
        atomicAdd(kl_sum, klb);
        atomicAdd(kl_cnt, (unsigned)n_valid_raw);
    }
}

__global__ void finalize_kernel(const float* __restrict__ kl_sum,
                                const unsigned int* __restrict__ kl_cnt,
                                float* __restrict__ out_kl) {
    unsigned c = *kl_cnt;
    if (c < 1u) c = 1u;
    // kl_u == kl_i (KL is eps-independent); (kl_u+kl_i)/2 == BETA * sum / count
    *out_kl = 0.25f * (*kl_sum) / (float)c;
}

extern "C" void kernel_launch(void* const* d_in, const int* in_sizes, int n_in,
                              void* d_out, int out_size, void* d_ws, size_t ws_size,
                              hipStream_t stream) {
    (void)in_sizes; (void)n_in; (void)out_size; (void)ws_size;
    const float* user_emb = (const float*)d_in[0];
    const float* item_emb = (const float*)d_in[1];
    const float* Wq       = (const float*)d_in[2];
    const float* Wk       = (const float*)d_in[3];
    const float* b_att    = (const float*)d_in[4];
    const float* v_att    = (const float*)d_in[5];
    const float* ln_u_g   = (const float*)d_in[6];
    const float* ln_u_b   = (const float*)d_in[7];
    const float* ln_i_g   = (const float*)d_in[8];
    const float* ln_i_b   = (const float*)d_in[9];
    const float* pred_W   = (const float*)d_in[10];
    const float* pred_b   = (const float*)d_in[11];
    const int* user_hist  = (const int*)d_in[12];
    const int* user_idx   = (const int*)d_in[13];
    const int* item_idx   = (const int*)d_in[14];
    float* out = (float*)d_out;

    // PT first (256-aligned rows; misalignment would straddle extra sectors)
    unsigned char* PT = (unsigned char*)d_ws;            // NI1*256 B (25.6 MB)
    float* qW    = (float*)(PT + (size_t)NI1 * 256);     // BATCH*D f32 (2 MB)
    float* accum = qW + (size_t)BATCH * D;               // [0] kl, [1] cnt
    unsigned short* WkTb = (unsigned short*)(accum + 4); // 128*128 bf16
    unsigned short* WqTb = WkTb + D * D;                 // 128*128 bf16

    wk_prep<<<256, 128, 0, stream>>>(Wk, Wq, WkTb, WqTb, accum);
    tables_kernel<<<KWBLOCKS + QWBLOCKS, 256, 0, stream>>>(
        item_emb, user_emb, user_idx, WkTb, WqTb, b_att, PT, qW);
    fused_kernel<<<BATCH, 256, 0, stream>>>(PT, qW, v_att, user_emb,
                                            item_emb, user_hist, user_idx,
                                            item_idx, ln_u_g, ln_u_b, ln_i_g,
                                            ln_i_b, pred_W, pred_b, out, accum,
                                            (unsigned int*)(accum + 1));
    finalize_kernel<<<1, 1, 0, stream>>>(accum, (const unsigned int*)(accum + 1),
                                         out + BATCH);
}

// Round 6
// 268.485 us; speedup vs baseline: 1.2407x; 1.2407x over previous
//
#include <hip/hip_runtime.h>
#include <hip/hip_bf16.h>
#include <math.h>

#define D 128
#define L 200
#define BATCH 4096
#define EPB 2                   // elements per block (fused)
#define NBLK (BATCH / EPB)      // 2048
#define N_ITEMS 100000
#define NI1 (N_ITEMS + 1)
#define KWBLOCKS 782            // ceil(NI1/128)
#define QWBLOCKS 32             // 4096/128
#define HALF_CNT (BATCH * L / 2)   // 409600, threefry counter split
#define TAU_INV 0.25f
#define SIG_Q 0.1f
// C_KL = log(SIG_P/SIG_Q) + SIG_Q^2/2 - 0.5  (SIG_P = 1)
#define C_KL 1.8075850929940455f
// fp8 e4m3 software decode: val = as_float((s<<31)|(e<<23)|(m<<20)) * 2^113 (x128 scale folded)
#define C_DEC 1.03845937e34f

typedef __attribute__((ext_vector_type(8))) short short8;
typedef __attribute__((ext_vector_type(4))) float float4v;
typedef __attribute__((ext_vector_type(2))) float f32x2;

#if defined(__has_builtin)
#if __has_builtin(__builtin_amdgcn_cvt_pk_f32_fp8) && __has_builtin(__builtin_amdgcn_cvt_pk_fp8_f32)
#define HWFP8 1
#endif
#endif
#ifndef HWFP8
#define HWFP8 0
#endif

// ---------------- bf16 / fp8 helpers ----------------
__device__ __forceinline__ unsigned short f2bf(float f) {
    unsigned x = __float_as_uint(f);
    unsigned r = (x + 0x7fffu + ((x >> 16) & 1u)) >> 16;  // RNE
    return (unsigned short)r;
}
// f32 -> fp8 e4m3fn (OCP), RNE; |x| < 448 guaranteed by data (~N(0,1.3) after x128)
__device__ __forceinline__ unsigned f2fp8(float x) {
    unsigned s = (__float_as_uint(x) >> 31) << 7;
    float ay = fabsf(x);
    unsigned b;
    if (ay < 0.015625f) {                       // subnormal: step 2^-9; n==8 carries to e=1
        b = (unsigned)__float2int_rn(ay * 512.0f);
    } else {
        unsigned u = __float_as_uint(ay);
        u += 0x7ffffu + ((u >> 20) & 1u);       // RNE at mantissa bit 20
        unsigned e = (u >> 23) - 120u;          // bias 127 -> 7
        b = (e << 3) | ((u >> 20) & 7u);
    }
    return b | s;
}

// pack 4 (already x128-scaled) floats into 4 fp8 bytes of one dword
__device__ __forceinline__ unsigned pack4fp8(float a, float b, float c, float d) {
#if HWFP8
    int r = __builtin_amdgcn_cvt_pk_fp8_f32(a, b, 0, false);
    r = __builtin_amdgcn_cvt_pk_fp8_f32(c, d, r, true);
    return (unsigned)r;
#else
    return f2fp8(a) | (f2fp8(b) << 8) | (f2fp8(c) << 16) | (f2fp8(d) << 24);
#endif
}

// decode 4 fp8 bytes -> two f32 pairs, each = true_value * 128
#if HWFP8
__device__ __forceinline__ void dec4p(unsigned x, f32x2& lo, f32x2& hi) {
    lo = __builtin_amdgcn_cvt_pk_f32_fp8(x, false);
    hi = __builtin_amdgcn_cvt_pk_f32_fp8(x, true);
}
#else
__device__ __forceinline__ void dec4p(unsigned x, f32x2& lo, f32x2& hi) {
    const float S = C_DEC * 128.f;
    lo.x = __uint_as_float(((x & 0x80u) << 24) | ((x & 0x7fu) << 20)) * S;
    lo.y = __uint_as_float(((x & 0x8000u) << 16) | ((x & 0x7f00u) << 12)) * S;
    hi.x = __uint_as_float(((x & 0x800000u) << 8) | ((x & 0x7f0000u) << 4)) * S;
    hi.y = __uint_as_float((x & 0x80000000u) | ((x & 0x7f000000u) >> 4)) * S;
}
#endif

__device__ __forceinline__ f32x2 pfma(f32x2 a, f32x2 b, f32x2 c) {
    return __builtin_elementwise_fma(a, b, c);
}

// 32-lane all-reduce sum: 4 DPP adds + 1 ds_swizzle
#define DPP_ADD(x, ctrl)                                                     \
    ((x) + __uint_as_float((unsigned)__builtin_amdgcn_update_dpp(            \
               0, (int)__float_as_uint(x), ctrl, 0xF, 0xF, true)))
__device__ __forceinline__ float red32(float x) {
    x = DPP_ADD(x, 0xB1);    // quad_perm [1,0,3,2]  : xor 1
    x = DPP_ADD(x, 0x4E);    // quad_perm [2,3,0,1]  : xor 2
    x = DPP_ADD(x, 0x141);   // row_half_mirror      : pairs 8-groups
    x = DPP_ADD(x, 0x140);   // row_mirror           : pairs 16-groups
    x += __uint_as_float((unsigned)__builtin_amdgcn_ds_swizzle(
        (int)__float_as_uint(x), 0x401F));   // xor 16 within 32
    return x;
}

// ---------------- JAX threefry2x32 (exact) ----------------
__device__ __forceinline__ unsigned rotl32(unsigned x, int r) {
    return (x << r) | (x >> (32 - r));
}

__device__ __forceinline__ void threefry2x32(unsigned k0, unsigned k1,
                                             unsigned x0, unsigned x1,
                                             unsigned& o0, unsigned& o1) {
    unsigned k2 = k0 ^ k1 ^ 0x1BD11BDAu;
    x0 += k0; x1 += k1;
#define TF_ROUND(r) { x0 += x1; x1 = rotl32(x1, r); x1 ^= x0; }
    TF_ROUND(13) TF_ROUND(15) TF_ROUND(26) TF_ROUND(6)
    x0 += k1; x1 += k2 + 1u;
    TF_ROUND(17) TF_ROUND(29) TF_ROUND(16) TF_ROUND(24)
    x0 += k2; x1 += k0 + 2u;
    TF_ROUND(13) TF_ROUND(15) TF_ROUND(26) TF_ROUND(6)
    x0 += k0; x1 += k1 + 3u;
    TF_ROUND(17) TF_ROUND(29) TF_ROUND(16) TF_ROUND(24)
    x0 += k1; x1 += k2 + 4u;
    TF_ROUND(13) TF_ROUND(15) TF_ROUND(26) TF_ROUND(6)
    x0 += k2; x1 += k0 + 5u;
#undef TF_ROUND
    o0 = x0; o1 = x1;
}

// XLA ErfInv32 (Giles) polynomial
__device__ float erfinv_f32(float x) {
    float w = -log1pf(-x * x);
    float p;
    if (w < 5.0f) {
        w -= 2.5f;
        p = 2.81022636e-08f;
        p = fmaf(p, w, 3.43273939e-07f);
        p = fmaf(p, w, -3.5233877e-06f);
        p = fmaf(p, w, -4.39150654e-06f);
        p = fmaf(p, w, 0.00021858087f);
        p = fmaf(p, w, -0.00125372503f);
        p = fmaf(p, w, -0.00417768164f);
        p = fmaf(p, w, 0.246640727f);
        p = fmaf(p, w, 1.50140941f);
    } else {
        w = sqrtf(w) - 3.0f;
        p = -0.000200214257f;
        p = fmaf(p, w, 0.000100950558f);
        p = fmaf(p, w, 0.00134934322f);
        p = fmaf(p, w, -0.00367342844f);
        p = fmaf(p, w, 0.00573950773f);
        p = fmaf(p, w, -0.0076224613f);
        p = fmaf(p, w, 0.00943887047f);
        p = fmaf(p, w, 1.00167406f);
        p = fmaf(p, w, 2.83297682f);
    }
    return p * x;
}

__device__ float bits_to_normal(unsigned bits) {
    float f = __uint_as_float((bits >> 9) | 0x3f800000u) - 1.0f;
    const float mn = -0.99999994f;
    float scale = 1.0f - mn;              // rounds to 2.0f, matches XLA
    float u = fmaf(f, scale, mn);
    u = fmaxf(mn, u);
    return 1.4142135623730951f * erfinv_f32(u);
}

// ---- prep: WkTb[n][k], WqTb[n][k] = bf16 transposes ----
__global__ __launch_bounds__(128) void wk_prep(const float* __restrict__ Wk,
                                               const float* __restrict__ Wq,
                                               unsigned short* __restrict__ WkTb,
                                               unsigned short* __restrict__ WqTb) {
    int n = blockIdx.x & 127;
    const float* src = (blockIdx.x < 128) ? Wk : Wq;
    unsigned short* dst = (blockIdx.x < 128) ? WkTb : WqTb;
    int k = threadIdx.x;
    dst[n * D + k] = f2bf(src[k * D + n]);
}

// ---- tables: PT packed rows (256 B/item): chunk c in [0,32):
//      bytes [8c..8c+3] = fp8(KW[row][4c..4c+3] * 128),
//      bytes [8c+4..8c+7] = fp8(item_emb[row][4c..4c+3] * 128).
//      KW computed TRANSPOSED (mfma(WkT, emb)) so each lane owns 4 consecutive
//      columns -> one packed dword. Full row image staged in LDS (XOR-swizzled
//      16B units) and streamed out as coalesced dwordx4.
//      Also qW = user_emb[user_idx]@Wq + b_att (f32). ----
__global__ __launch_bounds__(256) void tables_kernel(
    const float* __restrict__ item_emb, const float* __restrict__ user_emb,
    const int* __restrict__ user_idx,
    const unsigned short* __restrict__ WkTb, const unsigned short* __restrict__ WqTb,
    const float* __restrict__ b_att,
    unsigned char* __restrict__ PT, float* __restrict__ qW) {
    __shared__ unsigned char stage[128 * 256];   // 32 KB
    int t = threadIdx.x;
    int w = t >> 6, lane = t & 63;
    int lq = lane >> 4, lm = lane & 15;
    int bx = blockIdx.x;

    if (bx < KWBLOCKS) {
        int r0 = bx * 128;
        int rw = w * 32;                         // wave-local row base
        short8 afr[2][4];
#pragma unroll
        for (int tm = 0; tm < 2; tm++) {
            int rowl = rw + tm * 16 + lm;
            int row = r0 + rowl;
            bool ok = row < NI1;
            const float* src = item_emb + (size_t)row * D;
            unsigned sbase = rowl * 256;
            int rsw = rowl & 15;
#pragma unroll
            for (int kc = 0; kc < 4; kc++) {
                float4 a = ok ? *(const float4*)(src + kc * 32 + lq * 8)
                              : make_float4(0.f, 0.f, 0.f, 0.f);
                float4 c = ok ? *(const float4*)(src + kc * 32 + lq * 8 + 4)
                              : make_float4(0.f, 0.f, 0.f, 0.f);
                short8 f;
                f[0] = (short)f2bf(a.x); f[1] = (short)f2bf(a.y);
                f[2] = (short)f2bf(a.z); f[3] = (short)f2bf(a.w);
                f[4] = (short)f2bf(c.x); f[5] = (short)f2bf(c.y);
                f[6] = (short)f2bf(c.z); f[7] = (short)f2bf(c.w);
                afr[tm][kc] = f;
                // emb fp8 -> V slots of chunks c0, c0+1 (bytes 4-7 / 12-15 of unit u)
                int u = kc * 4 + lq;             // = (kc*8+lq*2)>>1
                unsigned* dst = (unsigned*)(stage + sbase + ((unsigned)(u ^ rsw) << 4));
                dst[1] = pack4fp8(a.x * 128.f, a.y * 128.f, a.z * 128.f, a.w * 128.f);
                dst[3] = pack4fp8(c.x * 128.f, c.y * 128.f, c.z * 128.f, c.w * 128.f);
            }
        }
        float4v acc[2][8];
#pragma unroll
        for (int tm = 0; tm < 2; tm++)
#pragma unroll
            for (int tn = 0; tn < 8; tn++) acc[tm][tn] = (float4v)(0.f);
#pragma unroll
        for (int tn = 0; tn < 8; tn++) {
#pragma unroll
            for (int kc = 0; kc < 4; kc++) {
                short8 bfr = *(const short8*)(WkTb + (tn * 16 + lm) * D + kc * 32 + lq * 8);
                // TRANSPOSED: D[m'=WkT row][n'=item row] => lane holds 4 consecutive KW cols
                acc[0][tn] = __builtin_amdgcn_mfma_f32_16x16x32_bf16(bfr, afr[0][kc], acc[0][tn], 0, 0, 0);
                acc[1][tn] = __builtin_amdgcn_mfma_f32_16x16x32_bf16(bfr, afr[1][kc], acc[1][tn], 0, 0, 0);
            }
        }
#pragma unroll
        for (int tm = 0; tm < 2; tm++) {
            int rowl = rw + tm * 16 + lm;        // n' = lane&15
            int rsw = rowl & 15;
            unsigned sbase = rowl * 256;
#pragma unroll
            for (int tn = 0; tn < 8; tn++) {
                unsigned dw = pack4fp8(acc[tm][tn][0] * 128.f, acc[tm][tn][1] * 128.f,
                                       acc[tm][tn][2] * 128.f, acc[tm][tn][3] * 128.f);
                int cc = 4 * tn + lq;            // chunk (4 consecutive dims)
                int u = cc >> 1;
                *(unsigned*)(stage + sbase + ((unsigned)(u ^ rsw) << 4) +
                             ((unsigned)(cc & 1) << 3)) = dw;
            }
        }
        __syncthreads();
        // coalesced write-out: 128 rows x 16 units of 16B
#pragma unroll
        for (int i = 0; i < 8; i++) {
            int gidx = i * 256 + t;
            int rowl = gidx >> 4, u = gidx & 15;
            int row = r0 + rowl;
            if (row < NI1) {
                float4 vv = *(const float4*)(stage + rowl * 256 +
                                             ((unsigned)(u ^ (rowl & 15)) << 4));
                *(float4*)(PT + (size_t)row * 256 + (unsigned)u * 16) = vv;
            }
        }
    } else {
        int r0 = (bx - KWBLOCKS) * 128 + w * 32;
        int urow0 = user_idx[r0 + lm];
        int urow1 = user_idx[r0 + 16 + lm];
        short8 afr[2][4];
#pragma unroll
        for (int tm = 0; tm < 2; tm++) {
            const float* src = user_emb + (size_t)(tm ? urow1 : urow0) * D;
#pragma unroll
            for (int kc = 0; kc < 4; kc++) {
                float4 a = *(const float4*)(src + kc * 32 + lq * 8);
                float4 c = *(const float4*)(src + kc * 32 + lq * 8 + 4);
                short8 f;
                f[0] = (short)f2bf(a.x); f[1] = (short)f2bf(a.y);
                f[2] = (short)f2bf(a.z); f[3] = (short)f2bf(a.w);
                f[4] = (short)f2bf(c.x); f[5] = (short)f2bf(c.y);
                f[6] = (short)f2bf(c.z); f[7] = (short)f2bf(c.w);
                afr[tm][kc] = f;
            }
        }
        float4v acc[2][8];
#pragma unroll
        for (int tm = 0; tm < 2; tm++)
#pragma unroll
            for (int tn = 0; tn < 8; tn++) acc[tm][tn] = (float4v)(0.f);
#pragma unroll
        for (int tn = 0; tn < 8; tn++) {
#pragma unroll
            for (int kc = 0; kc < 4; kc++) {
                short8 bfr = *(const short8*)(WqTb + (tn * 16 + lm) * D + kc * 32 + lq * 8);
                acc[0][tn] = __builtin_amdgcn_mfma_f32_16x16x32_bf16(afr[0][kc], bfr, acc[0][tn], 0, 0, 0);
                acc[1][tn] = __builtin_amdgcn_mfma_f32_16x16x32_bf16(afr[1][kc], bfr, acc[1][tn], 0, 0, 0);
            }
        }
#pragma unroll
        for (int tm = 0; tm < 2; tm++)
#pragma unroll
            for (int tn = 0; tn < 8; tn++) {
                float bv = b_att[tn * 16 + lm];
#pragma unroll
                for (int i = 0; i < 4; i++) {
                    int row = r0 + tm * 16 + lq * 4 + i;
                    qW[(size_t)row * D + tn * 16 + lm] = acc[tm][tn][i] + bv;
                }
            }
    }
}

// scaled-tanh coefficients: t = x*(1 - x^2/3 + 2x^4/15 - 17x^6/315) with x' = 128x
// folded: t' = x'*(1 + TC1*x'^2 + TC2*x'^4 + TC3*x'^6), t = t'/128 (folded into v)
#define TC3 (-1.2270929e-14f)   // -17/315 * 2^-42
#define TC2 (4.9670537e-10f)    //  2/15  * 2^-28
#define TC1 (-2.0345052e-5f)    // -1/3   * 2^-14

// ------- fused: 2 batch elements per block (dispatch/retire-throughput probe).
// Wall was pinned at ~4096 WG / 34 WG/us ~= 120us across R1/R3/R4/R5 regardless of
// VALU work, occupancy, prefetch depth -> hypothesis: WG dispatch/retire cap.
// Halving block count tests it. Also: NO global atomics (same-line kl_sum/kl_cnt
// atomics serialized block retirement); per-block partials + finalize reduce.
// NO min-waves clause (R2: forcing 64-VGPR cap -> 643MB scratch spills).
__global__ __launch_bounds__(256) void fused_kernel(
    const unsigned char* __restrict__ PT, const float* __restrict__ qW,
    const float* __restrict__ v_att,
    const float* __restrict__ user_emb, const float* __restrict__ item_emb,
    const int* __restrict__ user_hist, const int* __restrict__ user_idx,
    const int* __restrict__ item_idx,
    const float* __restrict__ ln_u_g, const float* __restrict__ ln_u_b,
    const float* __restrict__ ln_i_g, const float* __restrict__ ln_i_b,
    const float* __restrict__ pred_W, const float* __restrict__ pred_b,
    float* __restrict__ out, float* __restrict__ kl_part,
    float* __restrict__ cnt_part) {
    int b2 = blockIdx.x;               // handles batch elements 2*b2, 2*b2+1
    int t = threadIdx.x;
    int g = t >> 5, ln5 = t & 31, w_ = t >> 6, lane = t & 63;
    int e = g >> 2, gi = g & 3;        // element (wave-uniform), group-in-element
    __shared__ int refer[EPB * L];
    __shared__ float2 r12[EPB * L];    // exp(SIG_Q*eps) pre-factors
    __shared__ float4 gsA[8];          // per group: se, sw1, sw2, cnt
    __shared__ float2 gsB[8];          // per group: ss, ss2
    __shared__ float paccU[8][D], paccI[8][D];
    __shared__ float us_s[D];
    __shared__ float wredA[4], wredB[4], wredC[4];

    int u0 = user_idx[2 * b2], u1 = user_idx[2 * b2 + 1];
    int tgt0 = item_idx[2 * b2], tgt1 = item_idx[2 * b2 + 1];
    for (int i = t; i < EPB * L; i += 256) {
        int el = (i >= L);
        refer[i] = user_hist[(size_t)(el ? u1 : u0) * L + (i - el * L)];
    }

    int be = 2 * b2 + e;
    int tgt = e ? tgt1 : tgt0;         // wave-uniform
    float4 q4 = *(const float4*)(qW + (size_t)be * D + ln5 * 4);
    float4 v4 = *(const float4*)(v_att + ln5 * 4);
    // q scaled by 128 (x' domain), v scaled by 1/(128*tau)
    f32x2 qA = {q4.x * 128.f, q4.y * 128.f};
    f32x2 qB = {q4.z * 128.f, q4.w * 128.f};
    const float VS = TAU_INV / 128.f;
    f32x2 vAs = {v4.x * VS, v4.y * VS};
    f32x2 vBs = {v4.z * VS, v4.w * VS};

    __syncthreads();                   // refer[] ready

    // ---- Prologue: issue gathers for chunks 0..1 (10 loads in flight) ----
    int l0r = e * L + gi * 50;         // base into refer/r12; this group: 50 rows
    uint2 kv0[5], kv1[5];
    unsigned lnoff = (unsigned)(ln5 * 8);
#pragma unroll
    for (int j = 0; j < 5; j++) {
        unsigned it = (unsigned)refer[l0r + j];
        kv0[j] = *(const uint2*)(PT + ((it << 8) | lnoff));
    }
#pragma unroll
    for (int j = 0; j < 5; j++) {
        unsigned it = (unsigned)refer[l0r + 5 + j];
        kv1[j] = *(const uint2*)(PT + ((it << 8) | lnoff));
    }

    // ---- Phase A: r = exp(SIG_Q*eps) per slot; overlaps prologue gather latency.
    //      slot i of this block = batch slot f = b2*(2L) + i  (since be*L+l = 2*b2*L+i)
    for (int i = t; i < EPB * L; i += 256) {
        int f = b2 * (EPB * L) + i;
        unsigned o0, o1, bits1, bits2;
        if (f < HALF_CNT) {
            threefry2x32(0u, 1u, (unsigned)f, (unsigned)(f + HALF_CNT), o0, o1);
            bits1 = o0;
            threefry2x32(0u, 2u, (unsigned)f, (unsigned)(f + HALF_CNT), o0, o1);
            bits2 = o0;
        } else {
            threefry2x32(0u, 1u, (unsigned)(f - HALF_CNT), (unsigned)f, o0, o1);
            bits1 = o1;
            threefry2x32(0u, 2u, (unsigned)(f - HALF_CNT), (unsigned)f, o0, o1);
            bits2 = o1;
        }
        r12[i] = make_float2(__expf(SIG_Q * bits_to_normal(bits1)),
                             __expf(SIG_Q * bits_to_normal(bits2)));
    }
    __syncthreads();                   // r12[] ready

    // ---- Phase B: 10 chunks x 5 rows; two named buffers (no runtime reg-array
    //      indexing), refill right after consumption ----
    f32x2 aU01 = {0.f, 0.f}, aU23 = {0.f, 0.f};
    f32x2 aI01 = {0.f, 0.f}, aI23 = {0.f, 0.f};
    float se = 0.f, sw1 = 0.f, sw2 = 0.f, ss = 0.f, ss2 = 0.f, cn = 0.f;
    const f32x2 tc3v = {TC3, TC3}, tc2v = {TC2, TC2}, tc1v = {TC1, TC1};
    const f32x2 onev = {1.f, 1.f};

#define ROWS5(KV, CC)                                                         \
    _Pragma("unroll")                                                         \
    for (int j = 0; j < 5; j++) {                                             \
        int li = l0r + (CC) * 5 + j;                                          \
        unsigned kx = KV[j].x, ky = KV[j].y;                                  \
        f32x2 kA, kB;                                                         \
        dec4p(kx, kA, kB);                                                    \
        f32x2 xA = kA + qA, xB = kB + qB;                                     \
        f32x2 x2A = xA * xA, x2B = xB * xB;                                   \
        f32x2 pA = pfma(x2A, tc3v, tc2v);                                     \
        f32x2 pB = pfma(x2B, tc3v, tc2v);                                     \
        pA = pfma(x2A, pA, tc1v);                                             \
        pB = pfma(x2B, pB, tc1v);                                             \
        pA = pfma(x2A, pA, onev);                                             \
        pB = pfma(x2B, pB, onev);                                             \
        f32x2 pr = (xA * pA) * vAs;                                           \
        pr = pfma(xB * pB, vBs, pr);                                          \
        float s = red32(pr.x + pr.y);                                         \
        int it = refer[li];                                                   \
        bool valid = (it != tgt) && (it != N_ITEMS);                          \
        float ev = valid ? __expf(s) : 0.f;                                   \
        float sm = valid ? s : 0.f;                                           \
        se += ev; ss += sm; ss2 = fmaf(sm, sm, ss2);                          \
        cn += valid ? 1.f : 0.f;                                              \
        float2 r = r12[li];                                                   \
        float ed = ev * 0.0078125f;                                           \
        float w1 = ed * r.x, w2 = ed * r.y;                                   \
        sw1 += w1; sw2 += w2;                                                 \
        f32x2 vvA, vvB;                                                       \
        dec4p(ky, vvA, vvB);                                                  \
        f32x2 w1v = {w1, w1}, w2v = {w2, w2};                                 \
        aU01 = pfma(w1v, vvA, aU01); aU23 = pfma(w1v, vvB, aU23);             \
        aI01 = pfma(w2v, vvA, aI01); aI23 = pfma(w2v, vvB, aI23);             \
    }
#define PREF5(KV, CC)                                                         \
    _Pragma("unroll")                                                         \
    for (int j = 0; j < 5; j++) {                                             \
        unsigned it = (unsigned)refer[l0r + (CC) * 5 + j];                    \
        KV[j] = *(const uint2*)(PT + ((it << 8) | lnoff));                    \
    }

    for (int ph = 0; ph < 5; ph++) {
        int ca = 2 * ph;
        ROWS5(kv0, ca)
        if (ph < 4) { PREF5(kv0, ca + 2) }
        ROWS5(kv1, ca + 1)
        if (ph < 4) { PREF5(kv1, ca + 3) }
    }
#undef ROWS5
#undef PREF5

    if (ln5 == 0) {
        gsA[g] = make_float4(se, sw1, sw2, cn);
        gsB[g] = make_float2(ss, ss2);
    }
    *(float4*)&paccU[g][ln5 * 4] = make_float4(aU01.x, aU01.y, aU23.x, aU23.y);
    *(float4*)&paccI[g][ln5 * 4] = make_float4(aI01.x, aI01.y, aI23.x, aI23.y);
    __syncthreads();

    // ---- Phases C+D per element (sequential): scalars + ctx + LN + GMF + logit ----
    float klb_tot = 0.f, cnt_tot = 0.f;
    int d = t & 127, half = t >> 7;
#pragma unroll
    for (int e2 = 0; e2 < 2; e2++) {
        float sum_e = 0.f, sum_w1 = 0.f, sum_w2 = 0.f, cntf = 0.f, ssum = 0.f, ss2um = 0.f;
#pragma unroll
        for (int g2 = 0; g2 < 4; g2++) {
            float4 a = gsA[e2 * 4 + g2]; float2 c = gsB[e2 * 4 + g2];
            sum_e += a.x; sum_w1 += a.y; sum_w2 += a.z; cntf += a.w;
            ssum += c.x; ss2um += c.y;
        }
        int n_valid_raw = (int)(cntf + 0.5f);
        int n_valid = n_valid_raw < 1 ? 1 : n_valid_raw;
        float T = __logf(sum_e + 1e-30f) - __logf((float)n_valid);
        klb_tot += cntf * C_KL + 0.5f * (ss2um - 2.f * T * ssum + cntf * T * T);
        cnt_tot += cntf;
        float inv1 = 0.0078125f / (sum_w1 + 1e-14f);
        float inv2 = 0.0078125f / (sum_w2 + 1e-14f);

        float ctx = 0.f;
        if (half) {
#pragma unroll
            for (int g2 = 0; g2 < 4; g2++) ctx += paccI[e2 * 4 + g2][d];
            ctx *= inv2;
        } else {
#pragma unroll
            for (int g2 = 0; g2 < 4; g2++) ctx += paccU[e2 * 4 + g2][d];
            ctx *= inv1;
        }
        int ue = e2 ? u1 : u0, te = e2 ? tgt1 : tgt0;
        float own = ctx * (half ? item_emb[(size_t)te * D + d]
                                : user_emb[(size_t)ue * D + d]);
        float rsum = own;
#pragma unroll
        for (int m = 1; m < 64; m <<= 1) rsum += __shfl_xor(rsum, m);
        if (lane == 0) wredA[w_] = rsum;
        __syncthreads();
        float mean = (wredA[half * 2] + wredA[half * 2 + 1]) * (1.f / 128.f);
        float dv = own - mean;
        float vsum = dv * dv;
#pragma unroll
        for (int m = 1; m < 64; m <<= 1) vsum += __shfl_xor(vsum, m);
        if (lane == 0) wredB[w_] = vsum;
        __syncthreads();
        float var = (wredB[half * 2] + wredB[half * 2 + 1]) * (1.f / 128.f);
        float gg = half ? ln_i_g[d] : ln_u_g[d];
        float bb = half ? ln_i_b[d] : ln_u_b[d];
        float sl = dv * rsqrtf(var + 1e-5f) * gg + bb;
        if (!half) us_s[d] = sl;
        __syncthreads();
        float contrib = half ? (us_s[d] * sl * pred_W[d]) : 0.f;
#pragma unroll
        for (int m = 1; m < 64; m <<= 1) contrib += __shfl_xor(contrib, m);
        if (lane == 0) wredC[w_] = contrib;
        __syncthreads();
        if (t == 0) out[2 * b2 + e2] = wredC[2] + wredC[3] + pred_b[0];
    }
    if (t == 0) {
        kl_part[b2] = klb_tot;
        cnt_part[b2] = cnt_tot;
    }
}

__global__ __launch_bounds__(256) void finalize_kernel(
    const float* __restrict__ kl_part, const float* __restrict__ cnt_part,
    float* __restrict__ out_kl) {
    int t = threadIdx.x;
    float s = 0.f, c = 0.f;
    for (int i = t; i < NBLK; i += 256) { s += kl_part[i]; c += cnt_part[i]; }
#pragma unroll
    for (int m = 1; m < 64; m <<= 1) {
        s += __shfl_xor(s, m);
        c += __shfl_xor(c, m);
    }
    __shared__ float sh[8];
    int w = t >> 6, lane = t & 63;
    if (lane == 0) { sh[w * 2] = s; sh[w * 2 + 1] = c; }
    __syncthreads();
    if (t == 0) {
        float S = sh[0] + sh[2] + sh[4] + sh[6];
        float C = sh[1] + sh[3] + sh[5] + sh[7];
        if (C < 1.f) C = 1.f;
        // kl_u == kl_i (KL is eps-independent); (kl_u+kl_i)/2 == BETA * sum / count
        *out_kl = 0.25f * S / C;
    }
}

extern "C" void kernel_launch(void* const* d_in, const int* in_sizes, int n_in,
                              void* d_out, int out_size, void* d_ws, size_t ws_size,
                              hipStream_t stream) {
    (void)in_sizes; (void)n_in; (void)out_size; (void)ws_size;
    const float* user_emb = (const float*)d_in[0];
    const float* item_emb = (const float*)d_in[1];
    const float* Wq       = (const float*)d_in[2];
    const float* Wk       = (const float*)d_in[3];
    const float* b_att    = (const float*)d_in[4];
    const float* v_att    = (const float*)d_in[5];
    const float* ln_u_g   = (const float*)d_in[6];
    const float* ln_u_b   = (const float*)d_in[7];
    const float* ln_i_g   = (const float*)d_in[8];
    const float* ln_i_b   = (const float*)d_in[9];
    const float* pred_W   = (const float*)d_in[10];
    const float* pred_b   = (const float*)d_in[11];
    const int* user_hist  = (const int*)d_in[12];
    const int* user_idx   = (const int*)d_in[13];
    const int* item_idx   = (const int*)d_in[14];
    float* out = (float*)d_out;

    // PT first (256-aligned rows; misalignment would straddle extra sectors)
    unsigned char* PT = (unsigned char*)d_ws;            // NI1*256 B (25.6 MB)
    float* qW      = (float*)(PT + (size_t)NI1 * 256);   // BATCH*D f32 (2 MB)
    float* kl_part = qW + (size_t)BATCH * D;             // NBLK f32
    float* cnt_part = kl_part + NBLK;                    // NBLK f32
    unsigned short* WkTb = (unsigned short*)(cnt_part + NBLK); // 128*128 bf16
    unsigned short* WqTb = WkTb + D * D;                 // 128*128 bf16

    wk_prep<<<256, 128, 0, stream>>>(Wk, Wq, WkTb, WqTb);
    tables_kernel<<<KWBLOCKS + QWBLOCKS, 256, 0, stream>>>(
        item_emb, user_emb, user_idx, WkTb, WqTb, b_att, PT, qW);
    fused_kernel<<<NBLK, 256, 0, stream>>>(PT, qW, v_att, user_emb,
                                           item_emb, user_hist, user_idx,
                                           item_idx, ln_u_g, ln_u_b, ln_i_g,
                                           ln_i_b, pred_W, pred_b, out, kl_part,
                                           cnt_part);
    finalize_kernel<<<1, 256, 0, stream>>>(kl_part, cnt_part, out + BATCH);
}

// Round 8
// 267.640 us; speedup vs baseline: 1.2446x; 1.0032x over previous
//
#include <hip/hip_runtime.h>
#include <hip/hip_bf16.h>
#include <math.h>

#define D 128
#define L 200
#define BATCH 4096
#define EPB 4                   // elements per block (fused); wave w owns element w
#define NBLK (BATCH / EPB)      // 1024
#define N_ITEMS 100000
#define NI1 (N_ITEMS + 1)
#define KWBLOCKS 782            // ceil(NI1/128)
#define QWBLOCKS 32             // 4096/128
#define HALF_CNT (BATCH * L / 2)   // 409600, threefry counter split
#define TAU_INV 0.25f
#define SIG_Q 0.1f
// C_KL = log(SIG_P/SIG_Q) + SIG_Q^2/2 - 0.5  (SIG_P = 1)
#define C_KL 1.8075850929940455f
// fp8 e4m3 software decode: val = as_float((s<<31)|(e<<23)|(m<<20)) * 2^113 (x128 scale folded)
#define C_DEC 1.03845937e34f

typedef __attribute__((ext_vector_type(8))) short short8;
typedef __attribute__((ext_vector_type(4))) float float4v;
typedef __attribute__((ext_vector_type(2))) float f32x2;

#if defined(__has_builtin)
#if __has_builtin(__builtin_amdgcn_cvt_pk_f32_fp8) && __has_builtin(__builtin_amdgcn_cvt_pk_fp8_f32)
#define HWFP8 1
#endif
#endif
#ifndef HWFP8
#define HWFP8 0
#endif

// ---------------- bf16 / fp8 helpers ----------------
__device__ __forceinline__ unsigned short f2bf(float f) {
    unsigned x = __float_as_uint(f);
    unsigned r = (x + 0x7fffu + ((x >> 16) & 1u)) >> 16;  // RNE
    return (unsigned short)r;
}
// f32 -> fp8 e4m3fn (OCP), RNE; |x| < 448 guaranteed by data (~N(0,1.3) after x128)
__device__ __forceinline__ unsigned f2fp8(float x) {
    unsigned s = (__float_as_uint(x) >> 31) << 7;
    float ay = fabsf(x);
    unsigned b;
    if (ay < 0.015625f) {                       // subnormal: step 2^-9; n==8 carries to e=1
        b = (unsigned)__float2int_rn(ay * 512.0f);
    } else {
        unsigned u = __float_as_uint(ay);
        u += 0x7ffffu + ((u >> 20) & 1u);       // RNE at mantissa bit 20
        unsigned e = (u >> 23) - 120u;          // bias 127 -> 7
        b = (e << 3) | ((u >> 20) & 7u);
    }
    return b | s;
}

// pack 4 (already x128-scaled) floats into 4 fp8 bytes of one dword
__device__ __forceinline__ unsigned pack4fp8(float a, float b, float c, float d) {
#if HWFP8
    int r = __builtin_amdgcn_cvt_pk_fp8_f32(a, b, 0, false);
    r = __builtin_amdgcn_cvt_pk_fp8_f32(c, d, r, true);
    return (unsigned)r;
#else
    return f2fp8(a) | (f2fp8(b) << 8) | (f2fp8(c) << 16) | (f2fp8(d) << 24);
#endif
}

// decode 4 fp8 bytes -> two f32 pairs, each = true_value * 128
#if HWFP8
__device__ __forceinline__ void dec4p(unsigned x, f32x2& lo, f32x2& hi) {
    lo = __builtin_amdgcn_cvt_pk_f32_fp8(x, false);
    hi = __builtin_amdgcn_cvt_pk_f32_fp8(x, true);
}
#else
__device__ __forceinline__ void dec4p(unsigned x, f32x2& lo, f32x2& hi) {
    const float S = C_DEC * 128.f;
    lo.x = __uint_as_float(((x & 0x80u) << 24) | ((x & 0x7fu) << 20)) * S;
    lo.y = __uint_as_float(((x & 0x8000u) << 16) | ((x & 0x7f00u) << 12)) * S;
    hi.x = __uint_as_float(((x & 0x800000u) << 8) | ((x & 0x7f0000u) << 4)) * S;
    hi.y = __uint_as_float((x & 0x80000000u) | ((x & 0x7f000000u) >> 4)) * S;
}
#endif

__device__ __forceinline__ f32x2 pfma(f32x2 a, f32x2 b, f32x2 c) {
    return __builtin_elementwise_fma(a, b, c);
}

// 32-lane all-reduce sum: 4 DPP adds + 1 ds_swizzle
#define DPP_ADD(x, ctrl)                                                     \
    ((x) + __uint_as_float((unsigned)__builtin_amdgcn_update_dpp(            \
               0, (int)__float_as_uint(x), ctrl, 0xF, 0xF, true)))
__device__ __forceinline__ float red32(float x) {
    x = DPP_ADD(x, 0xB1);    // quad_perm [1,0,3,2]  : xor 1
    x = DPP_ADD(x, 0x4E);    // quad_perm [2,3,0,1]  : xor 2
    x = DPP_ADD(x, 0x141);   // row_half_mirror      : pairs 8-groups
    x = DPP_ADD(x, 0x140);   // row_mirror           : pairs 16-groups
    x += __uint_as_float((unsigned)__builtin_amdgcn_ds_swizzle(
        (int)__float_as_uint(x), 0x401F));   // xor 16 within 32
    return x;
}

// ---------------- JAX threefry2x32 (exact) ----------------
__device__ __forceinline__ unsigned rotl32(unsigned x, int r) {
    return (x << r) | (x >> (32 - r));
}

__device__ __forceinline__ void threefry2x32(unsigned k0, unsigned k1,
                                             unsigned x0, unsigned x1,
                                             unsigned& o0, unsigned& o1) {
    unsigned k2 = k0 ^ k1 ^ 0x1BD11BDAu;
    x0 += k0; x1 += k1;
#define TF_ROUND(r) { x0 += x1; x1 = rotl32(x1, r); x1 ^= x0; }
    TF_ROUND(13) TF_ROUND(15) TF_ROUND(26) TF_ROUND(6)
    x0 += k1; x1 += k2 + 1u;
    TF_ROUND(17) TF_ROUND(29) TF_ROUND(16) TF_ROUND(24)
    x0 += k2; x1 += k0 + 2u;
    TF_ROUND(13) TF_ROUND(15) TF_ROUND(26) TF_ROUND(6)
    x0 += k0; x1 += k1 + 3u;
    TF_ROUND(17) TF_ROUND(29) TF_ROUND(16) TF_ROUND(24)
    x0 += k1; x1 += k2 + 4u;
    TF_ROUND(13) TF_ROUND(15) TF_ROUND(26) TF_ROUND(6)
    x0 += k2; x1 += k0 + 5u;
#undef TF_ROUND
    o0 = x0; o1 = x1;
}

// XLA ErfInv32 (Giles) polynomial
__device__ float erfinv_f32(float x) {
    float w = -log1pf(-x * x);
    float p;
    if (w < 5.0f) {
        w -= 2.5f;
        p = 2.81022636e-08f;
        p = fmaf(p, w, 3.43273939e-07f);
        p = fmaf(p, w, -3.5233877e-06f);
        p = fmaf(p, w, -4.39150654e-06f);
        p = fmaf(p, w, 0.00021858087f);
        p = fmaf(p, w, -0.00125372503f);
        p = fmaf(p, w, -0.00417768164f);
        p = fmaf(p, w, 0.246640727f);
        p = fmaf(p, w, 1.50140941f);
    } else {
        w = sqrtf(w) - 3.0f;
        p = -0.000200214257f;
        p = fmaf(p, w, 0.000100950558f);
        p = fmaf(p, w, 0.00134934322f);
        p = fmaf(p, w, -0.00367342844f);
        p = fmaf(p, w, 0.00573950773f);
        p = fmaf(p, w, -0.0076224613f);
        p = fmaf(p, w, 0.00943887047f);
        p = fmaf(p, w, 1.00167406f);
        p = fmaf(p, w, 2.83297682f);
    }
    return p * x;
}

__device__ float bits_to_normal(unsigned bits) {
    float f = __uint_as_float((bits >> 9) | 0x3f800000u) - 1.0f;
    const float mn = -0.99999994f;
    float scale = 1.0f - mn;              // rounds to 2.0f, matches XLA
    float u = fmaf(f, scale, mn);
    u = fmaxf(mn, u);
    return 1.4142135623730951f * erfinv_f32(u);
}

// ---- prep: WkTb[n][k], WqTb[n][k] = bf16 transposes ----
__global__ __launch_bounds__(128) void wk_prep(const float* __restrict__ Wk,
                                               const float* __restrict__ Wq,
                                               unsigned short* __restrict__ WkTb,
                                               unsigned short* __restrict__ WqTb) {
    int n = blockIdx.x & 127;
    const float* src = (blockIdx.x < 128) ? Wk : Wq;
    unsigned short* dst = (blockIdx.x < 128) ? WkTb : WqTb;
    int k = threadIdx.x;
    dst[n * D + k] = f2bf(src[k * D + n]);
}

// ---- tables: PT packed rows (256 B/item): chunk c in [0,32):
//      bytes [8c..8c+3] = fp8(KW[row][4c..4c+3] * 128),
//      bytes [8c+4..8c+7] = fp8(item_emb[row][4c..4c+3] * 128).
//      KW computed TRANSPOSED (mfma(WkT, emb)) so each lane owns 4 consecutive
//      columns -> one packed dword. Full row image staged in LDS (XOR-swizzled
//      16B units) and streamed out as coalesced dwordx4.
//      Also qW = user_emb[user_idx]@Wq + b_att (f32). ----
__global__ __launch_bounds__(256) void tables_kernel(
    const float* __restrict__ item_emb, const float* __restrict__ user_emb,
    const int* __restrict__ user_idx,
    const unsigned short* __restrict__ WkTb, const unsigned short* __restrict__ WqTb,
    const float* __restrict__ b_att,
    unsigned char* __restrict__ PT, float* __restrict__ qW) {
    __shared__ unsigned char stage[128 * 256];   // 32 KB
    int t = threadIdx.x;
    int w = t >> 6, lane = t & 63;
    int lq = lane >> 4, lm = lane & 15;
    int bx = blockIdx.x;

    if (bx < KWBLOCKS) {
        int r0 = bx * 128;
        int rw = w * 32;                         // wave-local row base
        short8 afr[2][4];
#pragma unroll
        for (int tm = 0; tm < 2; tm++) {
            int rowl = rw + tm * 16 + lm;
            int row = r0 + rowl;
            bool ok = row < NI1;
            const float* src = item_emb + (size_t)row * D;
            unsigned sbase = rowl * 256;
            int rsw = rowl & 15;
#pragma unroll
            for (int kc = 0; kc < 4; kc++) {
                float4 a = ok ? *(const float4*)(src + kc * 32 + lq * 8)
                              : make_float4(0.f, 0.f, 0.f, 0.f);
                float4 c = ok ? *(const float4*)(src + kc * 32 + lq * 8 + 4)
                              : make_float4(0.f, 0.f, 0.f, 0.f);
                short8 f;
                f[0] = (short)f2bf(a.x); f[1] = (short)f2bf(a.y);
                f[2] = (short)f2bf(a.z); f[3] = (short)f2bf(a.w);
                f[4] = (short)f2bf(c.x); f[5] = (short)f2bf(c.y);
                f[6] = (short)f2bf(c.z); f[7] = (short)f2bf(c.w);
                afr[tm][kc] = f;
                // emb fp8 -> V slots of chunks c0, c0+1 (bytes 4-7 / 12-15 of unit u)
                int u = kc * 4 + lq;             // = (kc*8+lq*2)>>1
                unsigned* dst = (unsigned*)(stage + sbase + ((unsigned)(u ^ rsw) << 4));
                dst[1] = pack4fp8(a.x * 128.f, a.y * 128.f, a.z * 128.f, a.w * 128.f);
                dst[3] = pack4fp8(c.x * 128.f, c.y * 128.f, c.z * 128.f, c.w * 128.f);
            }
        }
        float4v acc[2][8];
#pragma unroll
        for (int tm = 0; tm < 2; tm++)
#pragma unroll
            for (int tn = 0; tn < 8; tn++) acc[tm][tn] = (float4v)(0.f);
#pragma unroll
        for (int tn = 0; tn < 8; tn++) {
#pragma unroll
            for (int kc = 0; kc < 4; kc++) {
                short8 bfr = *(const short8*)(WkTb + (tn * 16 + lm) * D + kc * 32 + lq * 8);
                // TRANSPOSED: D[m'=WkT row][n'=item row] => lane holds 4 consecutive KW cols
                acc[0][tn] = __builtin_amdgcn_mfma_f32_16x16x32_bf16(bfr, afr[0][kc], acc[0][tn], 0, 0, 0);
                acc[1][tn] = __builtin_amdgcn_mfma_f32_16x16x32_bf16(bfr, afr[1][kc], acc[1][tn], 0, 0, 0);
            }
        }
#pragma unroll
        for (int tm = 0; tm < 2; tm++) {
            int rowl = rw + tm * 16 + lm;        // n' = lane&15
            int rsw = rowl & 15;
            unsigned sbase = rowl * 256;
#pragma unroll
            for (int tn = 0; tn < 8; tn++) {
                unsigned dw = pack4fp8(acc[tm][tn][0] * 128.f, acc[tm][tn][1] * 128.f,
                                       acc[tm][tn][2] * 128.f, acc[tm][tn][3] * 128.f);
                int cc = 4 * tn + lq;            // chunk (4 consecutive dims)
                int u = cc >> 1;
                *(unsigned*)(stage + sbase + ((unsigned)(u ^ rsw) << 4) +
                             ((unsigned)(cc & 1) << 3)) = dw;
            }
        }
        __syncthreads();
        // coalesced write-out: 128 rows x 16 units of 16B
#pragma unroll
        for (int i = 0; i < 8; i++) {
            int gidx = i * 256 + t;
            int rowl = gidx >> 4, u = gidx & 15;
            int row = r0 + rowl;
            if (row < NI1) {
                float4 vv = *(const float4*)(stage + rowl * 256 +
                                             ((unsigned)(u ^ (rowl & 15)) << 4));
                *(float4*)(PT + (size_t)row * 256 + (unsigned)u * 16) = vv;
            }
        }
    } else {
        int r0 = (bx - KWBLOCKS) * 128 + w * 32;
        int urow0 = user_idx[r0 + lm];
        int urow1 = user_idx[r0 + 16 + lm];
        short8 afr[2][4];
#pragma unroll
        for (int tm = 0; tm < 2; tm++) {
            const float* src = user_emb + (size_t)(tm ? urow1 : urow0) * D;
#pragma unroll
            for (int kc = 0; kc < 4; kc++) {
                float4 a = *(const float4*)(src + kc * 32 + lq * 8);
                float4 c = *(const float4*)(src + kc * 32 + lq * 8 + 4);
                short8 f;
                f[0] = (short)f2bf(a.x); f[1] = (short)f2bf(a.y);
                f[2] = (short)f2bf(a.z); f[3] = (short)f2bf(a.w);
                f[4] = (short)f2bf(c.x); f[5] = (short)f2bf(c.y);
                f[6] = (short)f2bf(c.z); f[7] = (short)f2bf(c.w);
                afr[tm][kc] = f;
            }
        }
        float4v acc[2][8];
#pragma unroll
        for (int tm = 0; tm < 2; tm++)
#pragma unroll
            for (int tn = 0; tn < 8; tn++) acc[tm][tn] = (float4v)(0.f);
#pragma unroll
        for (int tn = 0; tn < 8; tn++) {
#pragma unroll
            for (int kc = 0; kc < 4; kc++) {
                short8 bfr = *(const short8*)(WqTb + (tn * 16 + lm) * D + kc * 32 + lq * 8);
                acc[0][tn] = __builtin_amdgcn_mfma_f32_16x16x32_bf16(afr[0][kc], bfr, acc[0][tn], 0, 0, 0);
                acc[1][tn] = __builtin_amdgcn_mfma_f32_16x16x32_bf16(afr[1][kc], bfr, acc[1][tn], 0, 0, 0);
            }
        }
#pragma unroll
        for (int tm = 0; tm < 2; tm++)
#pragma unroll
            for (int tn = 0; tn < 8; tn++) {
                float bv = b_att[tn * 16 + lm];
#pragma unroll
                for (int i = 0; i < 4; i++) {
                    int row = r0 + tm * 16 + lq * 4 + i;
                    qW[(size_t)row * D + tn * 16 + lm] = acc[tm][tn][i] + bv;
                }
            }
    }
}

// scaled-tanh coefficients: t = x*(1 - x^2/3 + 2x^4/15 - 17x^6/315) with x' = 128x
// folded: t' = x'*(1 + TC1*x'^2 + TC2*x'^4 + TC3*x'^6), t = t'/128 (folded into v)
#define TC3 (-1.2270929e-14f)   // -17/315 * 2^-42
#define TC2 (4.9670537e-10f)    //  2/15  * 2^-28
#define TC1 (-2.0345052e-5f)    // -1/3   * 2^-14

// ------- fused: 4 batch elements per block (wave w owns element w; its two
// 32-lane groups stream 100 rows each). R6 confirmed WG dispatch/retire cap at
// ~34 WG/us: 2048 WG -> 61us, exactly on the line. 1024 WG -> 30us dispatch
// floor; next floor is VALU (~45us measured busy). Per-block KL partials; no
// global atomics. NO min-waves clause (R2: 64-VGPR cap -> 643MB scratch spills).
__global__ __launch_bounds__(256) void fused_kernel(
    const unsigned char* __restrict__ PT, const float* __restrict__ qW,
    const float* __restrict__ v_att,
    const float* __restrict__ user_emb, const float* __restrict__ item_emb,
    const int* __restrict__ user_hist, const int* __restrict__ user_idx,
    const int* __restrict__ item_idx,
    const float* __restrict__ ln_u_g, const float* __restrict__ ln_u_b,
    const float* __restrict__ ln_i_g, const float* __restrict__ ln_i_b,
    const float* __restrict__ pred_W, const float* __restrict__ pred_b,
    float* __restrict__ out, float* __restrict__ kl_part,
    float* __restrict__ cnt_part) {
    int b4 = blockIdx.x;               // handles batch elements EPB*b4 .. EPB*b4+3
    int t = threadIdx.x;
    int g = t >> 5, ln5 = t & 31, w_ = t >> 6, lane = t & 63;
    int e = g >> 1, gi = g & 1;        // element == wave id; group-in-element
    __shared__ int refer[EPB * L];
    __shared__ float2 r12[EPB * L];    // exp(SIG_Q*eps) pre-factors
    __shared__ float4 gsA[8];          // per group: se, sw1, sw2, cnt
    __shared__ float2 gsB[8];          // per group: ss, ss2
    __shared__ float paccU[8][D], paccI[8][D];
    __shared__ float us_s[D];
    __shared__ float wredA[4], wredB[4], wredC[4];

    if (t < L) {
#pragma unroll
        for (int e0 = 0; e0 < EPB; e0++) {
            int ue = user_idx[EPB * b4 + e0];
            refer[e0 * L + t] = user_hist[(size_t)ue * L + t];
        }
    }

    int be = EPB * b4 + e;
    int tgt = item_idx[be];            // wave-uniform
    float4 q4 = *(const float4*)(qW + (size_t)be * D + ln5 * 4);
    float4 v4 = *(const float4*)(v_att + ln5 * 4);
    // q scaled by 128 (x' domain), v scaled by 1/(128*tau)
    f32x2 qA = {q4.x * 128.f, q4.y * 128.f};
    f32x2 qB = {q4.z * 128.f, q4.w * 128.f};
    const float VS = TAU_INV / 128.f;
    f32x2 vAs = {v4.x * VS, v4.y * VS};
    f32x2 vBs = {v4.z * VS, v4.w * VS};

    __syncthreads();                   // refer[] ready

    // ---- Prologue: issue gathers for chunks 0..1 (10 loads in flight) ----
    int l0r = e * L + gi * 100;        // base into refer/r12; this group: 100 rows
    uint2 kv0[5], kv1[5];
    unsigned lnoff = (unsigned)(ln5 * 8);
#pragma unroll
    for (int j = 0; j < 5; j++) {
        unsigned it = (unsigned)refer[l0r + j];
        kv0[j] = *(const uint2*)(PT + ((it << 8) | lnoff));
    }
#pragma unroll
    for (int j = 0; j < 5; j++) {
        unsigned it = (unsigned)refer[l0r + 5 + j];
        kv1[j] = *(const uint2*)(PT + ((it << 8) | lnoff));
    }

    // ---- Phase A: r = exp(SIG_Q*eps) per slot; overlaps prologue gather latency.
    //      block slot i -> batch slot f = b4*(EPB*L) + i  (be*L+l == EPB*b4*L+i)
    for (int i = t; i < EPB * L; i += 256) {
        int f = b4 * (EPB * L) + i;
        unsigned o0, o1, bits1, bits2;
        if (f < HALF_CNT) {
            threefry2x32(0u, 1u, (unsigned)f, (unsigned)(f + HALF_CNT), o0, o1);
            bits1 = o0;
            threefry2x32(0u, 2u, (unsigned)f, (unsigned)(f + HALF_CNT), o0, o1);
            bits2 = o0;
        } else {
            threefry2x32(0u, 1u, (unsigned)(f - HALF_CNT), (unsigned)f, o0, o1);
            bits1 = o1;
            threefry2x32(0u, 2u, (unsigned)(f - HALF_CNT), (unsigned)f, o0, o1);
            bits2 = o1;
        }
        r12[i] = make_float2(__expf(SIG_Q * bits_to_normal(bits1)),
                             __expf(SIG_Q * bits_to_normal(bits2)));
    }
    __syncthreads();                   // r12[] ready

    // ---- Phase B: 20 chunks x 5 rows; two named buffers (no runtime reg-array
    //      indexing), refill right after consumption ----
    f32x2 aU01 = {0.f, 0.f}, aU23 = {0.f, 0.f};
    f32x2 aI01 = {0.f, 0.f}, aI23 = {0.f, 0.f};
    float se = 0.f, sw1 = 0.f, sw2 = 0.f, ss = 0.f, ss2 = 0.f, cn = 0.f;
    const f32x2 tc3v = {TC3, TC3}, tc2v = {TC2, TC2}, tc1v = {TC1, TC1};
    const f32x2 onev = {1.f, 1.f};

#define ROWS5(KV, CC)                                                         \
    _Pragma("unroll")                                                         \
    for (int j = 0; j < 5; j++) {                                             \
        int li = l0r + (CC) * 5 + j;                                          \
        unsigned kx = KV[j].x, ky = KV[j].y;                                  \
        f32x2 kA, kB;                                                         \
        dec4p(kx, kA, kB);                                                    \
        f32x2 xA = kA + qA, xB = kB + qB;                                     \
        f32x2 x2A = xA * xA, x2B = xB * xB;                                   \
        f32x2 pA = pfma(x2A, tc3v, tc2v);                                     \
        f32x2 pB = pfma(x2B, tc3v, tc2v);                                     \
        pA = pfma(x2A, pA, tc1v);                                             \
        pB = pfma(x2B, pB, tc1v);                                             \
        pA = pfma(x2A, pA, onev);                                             \
        pB = pfma(x2B, pB, onev);                                             \
        f32x2 pr = (xA * pA) * vAs;                                           \
        pr = pfma(xB * pB, vBs, pr);                                          \
        float s = red32(pr.x + pr.y);                                         \
        int it = refer[li];                                                   \
        bool valid = (it != tgt) && (it != N_ITEMS);                          \
        float ev = valid ? __expf(s) : 0.f;                                   \
        float sm = valid ? s : 0.f;                                           \
        se += ev; ss += sm; ss2 = fmaf(sm, sm, ss2);                          \
        cn += valid ? 1.f : 0.f;                                              \
        float2 r = r12[li];                                                   \
        float ed = ev * 0.0078125f;                                           \
        float w1 = ed * r.x, w2 = ed * r.y;                                   \
        sw1 += w1; sw2 += w2;                                                 \
        f32x2 vvA, vvB;                                                       \
        dec4p(ky, vvA, vvB);                                                  \
        f32x2 w1v = {w1, w1}, w2v = {w2, w2};                                 \
        aU01 = pfma(w1v, vvA, aU01); aU23 = pfma(w1v, vvB, aU23);             \
        aI01 = pfma(w2v, vvA, aI01); aI23 = pfma(w2v, vvB, aI23);             \
    }
#define PREF5(KV, CC)                                                         \
    _Pragma("unroll")                                                         \
    for (int j = 0; j < 5; j++) {                                             \
        unsigned it = (unsigned)refer[l0r + (CC) * 5 + j];                    \
        KV[j] = *(const uint2*)(PT + ((it << 8) | lnoff));                    \
    }

    for (int ph = 0; ph < 10; ph++) {
        int ca = 2 * ph;
        ROWS5(kv0, ca)
        if (ph < 9) { PREF5(kv0, ca + 2) }
        ROWS5(kv1, ca + 1)
        if (ph < 9) { PREF5(kv1, ca + 3) }
    }
#undef ROWS5
#undef PREF5

    if (ln5 == 0) {
        gsA[g] = make_float4(se, sw1, sw2, cn);
        gsB[g] = make_float2(ss, ss2);
    }
    *(float4*)&paccU[g][ln5 * 4] = make_float4(aU01.x, aU01.y, aU23.x, aU23.y);
    *(float4*)&paccI[g][ln5 * 4] = make_float4(aI01.x, aI01.y, aI23.x, aI23.y);
    __syncthreads();

    // ---- Phases C+D per element (sequential): scalars + ctx + LN + GMF + logit ----
    float klb_tot = 0.f, cnt_tot = 0.f;
    int d = t & 127, half = t >> 7;
#pragma unroll
    for (int e2 = 0; e2 < EPB; e2++) {
        float sum_e = 0.f, sum_w1 = 0.f, sum_w2 = 0.f, cntf = 0.f, ssum = 0.f, ss2um = 0.f;
#pragma unroll
        for (int g2 = 0; g2 < 2; g2++) {
            float4 a = gsA[e2 * 2 + g2]; float2 c = gsB[e2 * 2 + g2];
            sum_e += a.x; sum_w1 += a.y; sum_w2 += a.z; cntf += a.w;
            ssum += c.x; ss2um += c.y;
        }
        int n_valid_raw = (int)(cntf + 0.5f);
        int n_valid = n_valid_raw < 1 ? 1 : n_valid_raw;
        float T = __logf(sum_e + 1e-30f) - __logf((float)n_valid);
        klb_tot += cntf * C_KL + 0.5f * (ss2um - 2.f * T * ssum + cntf * T * T);
        cnt_tot += cntf;
        float inv1 = 0.0078125f / (sum_w1 + 1e-14f);
        float inv2 = 0.0078125f / (sum_w2 + 1e-14f);

        float ctx = 0.f;
        if (half) {
#pragma unroll
            for (int g2 = 0; g2 < 2; g2++) ctx += paccI[e2 * 2 + g2][d];
            ctx *= inv2;
        } else {
#pragma unroll
            for (int g2 = 0; g2 < 2; g2++) ctx += paccU[e2 * 2 + g2][d];
            ctx *= inv1;
        }
        int ue = user_idx[EPB * b4 + e2], te = item_idx[EPB * b4 + e2];
        float own = ctx * (half ? item_emb[(size_t)te * D + d]
                                : user_emb[(size_t)ue * D + d]);
        float rsum = own;
#pragma unroll
        for (int m = 1; m < 64; m <<= 1) rsum += __shfl_xor(rsum, m);
        if (lane == 0) wredA[w_] = rsum;
        __syncthreads();
        float mean = (wredA[half * 2] + wredA[half * 2 + 1]) * (1.f / 128.f);
        float dv = own - mean;
        float vsum = dv * dv;
#pragma unroll
        for (int m = 1; m < 64; m <<= 1) vsum += __shfl_xor(vsum, m);
        if (lane == 0) wredB[w_] = vsum;
        __syncthreads();
        float var = (wredB[half * 2] + wredB[half * 2 + 1]) * (1.f / 128.f);
        float gg = half ? ln_i_g[d] : ln_u_g[d];
        float bb = half ? ln_i_b[d] : ln_u_b[d];
        float sl = dv * rsqrtf(var + 1e-5f) * gg + bb;
        if (!half) us_s[d] = sl;
        __syncthreads();
        float contrib = half ? (us_s[d] * sl * pred_W[d]) : 0.f;
#pragma unroll
        for (int m = 1; m < 64; m <<= 1) contrib += __shfl_xor(contrib, m);
        if (lane == 0) wredC[w_] = contrib;
        __syncthreads();
        if (t == 0) out[EPB * b4 + e2] = wredC[2] + wredC[3] + pred_b[0];
    }
    if (t == 0) {
        kl_part[b4] = klb_tot;
        cnt_part[b4] = cnt_tot;
    }
}

__global__ __launch_bounds__(256) void finalize_kernel(
    const float* __restrict__ kl_part, const float* __restrict__ cnt_part,
    float* __restrict__ out_kl) {
    int t = threadIdx.x;
    float s = 0.f, c = 0.f;
    for (int i = t; i < NBLK; i += 256) { s += kl_part[i]; c += cnt_part[i]; }
#pragma unroll
    for (int m = 1; m < 64; m <<= 1) {
        s += __shfl_xor(s, m);
        c += __shfl_xor(c, m);
    }
    __shared__ float sh[8];
    int w = t >> 6, lane = t & 63;
    if (lane == 0) { sh[w * 2] = s; sh[w * 2 + 1] = c; }
    __syncthreads();
    if (t == 0) {
        float S = sh[0] + sh[2] + sh[4] + sh[6];
        float C = sh[1] + sh[3] + sh[5] + sh[7];
        if (C < 1.f) C = 1.f;
        // kl_u == kl_i (KL is eps-independent); (kl_u+kl_i)/2 == BETA * sum / count
        *out_kl = 0.25f * S / C;
    }
}

extern "C" void kernel_launch(void* const* d_in, const int* in_sizes, int n_in,
                              void* d_out, int out_size, void* d_ws, size_t ws_size,
                              hipStream_t stream) {
    (void)in_sizes; (void)n_in; (void)out_size; (void)ws_size;
    const float* user_emb = (const float*)d_in[0];
    const float* item_emb = (const float*)d_in[1];
    const float* Wq       = (const float*)d_in[2];
    const float* Wk       = (const float*)d_in[3];
    const float* b_att    = (const float*)d_in[4];
    const float* v_att    = (const float*)d_in[5];
    const float* ln_u_g   = (const float*)d_in[6];
    const float* ln_u_b   = (const float*)d_in[7];
    const float* ln_i_g   = (const float*)d_in[8];
    const float* ln_i_b   = (const float*)d_in[9];
    const float* pred_W   = (const float*)d_in[10];
    const float* pred_b   = (const float*)d_in[11];
    const int* user_hist  = (const int*)d_in[12];
    const int* user_idx   = (const int*)d_in[13];
    const int* item_idx   = (const int*)d_in[14];
    float* out = (float*)d_out;

    // PT first (256-aligned rows; misalignment would straddle extra sectors)
    unsigned char* PT = (unsigned char*)d_ws;            // NI1*256 B (25.6 MB)
    float* qW      = (float*)(PT + (size_t)NI1 * 256);   // BATCH*D f32 (2 MB)
    float* kl_part = qW + (size_t)BATCH * D;             // NBLK f32
    float* cnt_part = kl_part + NBLK;                    // NBLK f32
    unsigned short* WkTb = (unsigned short*)(cnt_part + NBLK); // 128*128 bf16
    unsigned short* WqTb = WkTb + D * D;                 // 128*128 bf16

    wk_prep<<<256, 128, 0, stream>>>(Wk, Wq, WkTb, WqTb);
    tables_kernel<<<KWBLOCKS + QWBLOCKS, 256, 0, stream>>>(
        item_emb, user_emb, user_idx, WkTb, WqTb, b_att, PT, qW);
    fused_kernel<<<NBLK, 256, 0, stream>>>(PT, qW, v_att, user_emb,
                                           item_emb, user_hist, user_idx,
                                           item_idx, ln_u_g, ln_u_b, ln_i_g,
                                           ln_i_b, pred_W, pred_b, out, kl_part,
                                           cnt_part);
    finalize_kernel<<<1, 256, 0, stream>>>(kl_part, cnt_part, out + BATCH);
}